// Round 3
// baseline (483.706 us; speedup 1.0000x reference)
//
#include <hip/hip_runtime.h>

// LSTM: T=512, B=4096, I=10, H=20. Gate order i,f,g,o (PyTorch).
// R3: forced v_pk_fma_f32 via inline asm (R2's elementwise_fma likely
// scalarized: VALUBusy 44% @ 288us = 2x essential issue), ds_read_b128 h
// loads, clamp-free PF=4 prefetch with peeled tail.
// Still: 1-wave blocks (BPB=3, 60 lanes), no __syncthreads, weights in VGPRs.

#define T_STEPS 512
#define BATCH   4096
#define ISZ     10
#define HSZ     20
#define BPB     3    // batch per (one-wave) block: 20*3 = 60 active lanes
#define PF      4    // x prefetch depth (steps); also the unroll factor

typedef float v2f __attribute__((ext_vector_type(2)));
typedef float v4f __attribute__((ext_vector_type(4)));

// d += a*b on a VGPR pair — one VOP3P instr, 2 lanes of fp32.
__device__ __forceinline__ void pk_fma(v2f& d, v2f a, v2f b) {
    asm("v_pk_fma_f32 %0, %1, %2, %0" : "+v"(d) : "v"(a), "v"(b));
}

#if defined(__has_builtin)
#if __has_builtin(__builtin_amdgcn_exp2f)
#define FAST_EXP2(x) __builtin_amdgcn_exp2f(x)
#endif
#if __has_builtin(__builtin_amdgcn_rcpf)
#define FAST_RCP(x) __builtin_amdgcn_rcpf(x)
#endif
#endif
#ifndef FAST_EXP2
#define FAST_EXP2(x) exp2f(x)
#endif
#ifndef FAST_RCP
#define FAST_RCP(x) (1.0f/(x))
#endif

__device__ __forceinline__ float sigm_f(float x) {
    return FAST_RCP(1.0f + FAST_EXP2(x * -1.4426950408889634f));
}
__device__ __forceinline__ float tanh_f(float x) {
    return 2.0f * FAST_RCP(1.0f + FAST_EXP2(x * -2.8853900817779268f)) - 1.0f;
}

__global__ __launch_bounds__(64, 1) void lstm_fused_kernel(
    const float* __restrict__ x,    // [T, B, I]
    const float* __restrict__ h0,   // [B, H]
    const float* __restrict__ c0,   // [B, H]
    const float* __restrict__ Wih,  // [4H, I]
    const float* __restrict__ Whh,  // [4H, H]
    const float* __restrict__ bih,  // [4H]
    const float* __restrict__ bhh,  // [4H]
    float* __restrict__ out)        // [T*B*H] ++ [B*H] ++ [B*H]
{
    // 24-float rows: 96 B -> 16B-aligned rows for ds_read_b128; row banks
    // 0/24/16 keep cross-b aliasing <=3-way on the single write/step.
    __shared__ __align__(16) float hbuf[BPB][24];

    const int tid = threadIdx.x;
    const int b   = tid / HSZ;           // 0..3 (3 is idle)
    const int j   = tid % HSZ;           // 0..19
    const int gb  = blockIdx.x * BPB + b;
    if (tid >= BPB * HSZ || gb >= BATCH) return;

    // ---- weights into VGPR pairs: wv[r][0..4]=Wih row, [5..14]=Whh row
    v2f wv[4][15];
    float bias[4];
#pragma unroll
    for (int r = 0; r < 4; ++r) {
        const int row = r * HSZ + j;
        const v2f* wi = (const v2f*)(Wih + row * ISZ);   // 40B*row -> 8B aligned
        const v2f* wh = (const v2f*)(Whh + row * HSZ);   // 80B*row -> 8B aligned
#pragma unroll
        for (int k = 0; k < 5; ++k)  wv[r][k] = wi[k];
#pragma unroll
        for (int k = 0; k < 10; ++k) wv[r][5 + k] = wh[k];
        bias[r] = bih[row] + bhh[row];
    }

    float c = c0[(size_t)gb * HSZ + j];
    hbuf[b][j] = h0[(size_t)gb * HSZ + j];   // wave-synchronous init

    const int XSTEP = BATCH * ISZ;               // floats per timestep of x
    const int OSTEP = BATCH * HSZ;               // floats per timestep of out
    const float* xpf = x + (size_t)gb * ISZ;     // prefetch cursor (step t)
    float* outp = out + (size_t)gb * HSZ + j;

    // ---- prologue: fill circular register buffer with x[0..PF-1]
    v2f nx[PF][5];
#pragma unroll
    for (int p = 0; p < PF; ++p) {
        const v2f* xp = (const v2f*)xpf;
#pragma unroll
        for (int q = 0; q < 5; ++q) nx[p][q] = xp[q];
        xpf += XSTEP;
    }
    // xpf now points at x[PF] — exactly the next step to prefetch.

    const v4f* hrow = (const v4f*)(&hbuf[b][0]);
    float hn = hbuf[b][j];

    auto do_step = [&](int u, bool prefetch) {
        // 1) issue h reads early (critical path): 5x ds_read_b128
        v4f hv4[5];
#pragma unroll
        for (int q = 0; q < 5; ++q) hv4[q] = hrow[q];
        const v2f* hv = (const v2f*)hv4;   // same layout, 10 pairs

        // 2) x-part MACs (no h dependency -> fills LDS read latency)
        v2f a[4];
#pragma unroll
        for (int r = 0; r < 4; ++r) {
            a[r] = (v2f){bias[r], 0.0f};
#pragma unroll
            for (int k = 0; k < 5; ++k) pk_fma(a[r], wv[r][k], nx[u][k]);
        }

        // 3) refill slot u with x[t+PF] (main loop only; always in-bounds)
        if (prefetch) {
            const v2f* xp = (const v2f*)xpf;
#pragma unroll
            for (int q = 0; q < 5; ++q) nx[u][q] = xp[q];
            xpf += XSTEP;
        }

        // 4) h-part MACs
#pragma unroll
        for (int r = 0; r < 4; ++r) {
#pragma unroll
            for (int k = 0; k < 10; ++k) pk_fma(a[r], wv[r][5 + k], hv[k]);
        }

        const float ig = sigm_f(a[0].x + a[0].y);
        const float fg = sigm_f(a[1].x + a[1].y);
        const float gg = tanh_f(a[2].x + a[2].y);
        const float og = sigm_f(a[3].x + a[3].y);
        c  = fg * c + ig * gg;
        hn = og * tanh_f(c);

        hbuf[b][j] = hn;        // publish h_{t+1} (wave-synchronous, in-order LDS)
        *outp = hn;             // coalesced 60-dword burst
        outp += OSTEP;
    };

    // main: 127 iters x 4 steps, prefetching t+4 (max t prefetched = 511)
    for (int it = 0; it < (T_STEPS - PF) / PF; ++it) {
#pragma unroll
        for (int u = 0; u < PF; ++u) do_step(u, true);
    }
    // tail: last PF steps, no prefetch
#pragma unroll
    for (int u = 0; u < PF; ++u) do_step(u, false);

    // tail: final h then final c
    const size_t tail = (size_t)T_STEPS * BATCH * HSZ;
    out[tail + (size_t)gb * HSZ + j] = hn;
    out[tail + (size_t)BATCH * HSZ + (size_t)gb * HSZ + j] = c;
}

extern "C" void kernel_launch(void* const* d_in, const int* in_sizes, int n_in,
                              void* d_out, int out_size, void* d_ws, size_t ws_size,
                              hipStream_t stream) {
    const float* x   = (const float*)d_in[0];
    const float* h0  = (const float*)d_in[1];
    const float* c0  = (const float*)d_in[2];
    const float* Wih = (const float*)d_in[3];
    const float* Whh = (const float*)d_in[4];
    const float* bih = (const float*)d_in[5];
    const float* bhh = (const float*)d_in[6];
    float* out = (float*)d_out;

    const int nblk = (BATCH + BPB - 1) / BPB;   // 1366 one-wave blocks
    lstm_fused_kernel<<<nblk, 64, 0, stream>>>(x, h0, c0, Wih, Whh, bih, bhh, out);
}